// Round 9
// baseline (157.113 us; speedup 1.0000x reference)
//
#include <hip/hip_runtime.h>
#include <hip/hip_bf16.h>

#define BS 4
#define SEQ 2048
#define DIM 512
#define HEADS 8
#define HD 64
#define ROWS (BS*SEQ)   // 8192
// (1/sqrt(64)) * log2(e) folded into K at projection time
#define SCL2E 0.1803368801111244f
#define NEGB (-1.4426950408889634e6f)   // -1e6 * log2(e)

typedef __attribute__((ext_vector_type(8))) short bf16x8;
typedef __attribute__((ext_vector_type(4))) short bf16x4;
typedef __attribute__((ext_vector_type(4))) float floatx4;
typedef unsigned short u16;
typedef unsigned int u32;

__device__ __forceinline__ u16 f2bf(float f) {
    union { float f; unsigned u; } v; v.f = f;
    unsigned r = v.u + 0x7fff + ((v.u >> 16) & 1);
    return (u16)(r >> 16);
}

__device__ __forceinline__ unsigned pack2bf(float a, float b) {
#if __has_builtin(__builtin_amdgcn_cvt_pk_bf16_f32)
    typedef __attribute__((ext_vector_type(2))) __bf16 bf2;
    union { bf2 v; unsigned u; } cv;
    cv.v = __builtin_amdgcn_cvt_pk_bf16_f32(a, b);
    return cv.u;
#else
    return (unsigned)f2bf(a) | ((unsigned)f2bf(b) << 16);
#endif
}

__device__ __forceinline__ float fexp2(float x) {
#if __has_builtin(__builtin_amdgcn_exp2f)
    return __builtin_amdgcn_exp2f(x);     // raw v_exp_f32
#else
    return __expf(x * 0.6931471805599453f);
#endif
}

// async global->LDS, 16B per lane. g is PER-LANE global addr, l is wave-uniform.
__device__ __forceinline__ void gload16(const u16* g, u16* l) {
    __builtin_amdgcn_global_load_lds(
        (const __attribute__((address_space(1))) u32*)g,
        (__attribute__((address_space(3))) u32*)l, 16, 0, 0);
}

// ---------------- fp32 -> bf16 conversion; mask -> exp2-domain bias ---------
__global__ __launch_bounds__(256) void convert_all(
    const float* __restrict__ x, const float* __restrict__ Wq,
    const float* __restrict__ Wk, const float* __restrict__ Wv,
    const float* __restrict__ Wo, const int* __restrict__ mask,
    u16* __restrict__ xb, u16* __restrict__ wqb,
    u16* __restrict__ wkb, u16* __restrict__ wvb,
    u16* __restrict__ wob, float* __restrict__ biasf)
{
    int i = blockIdx.x * 256 + threadIdx.x;
    if (i < 1048576 + 262144) {
        const float* src; u16* dst; int off;
        if (i < 1048576) { src = x; dst = xb; off = i; }
        else {
            int j = i - 1048576; int seg = j >> 16; off = j & 65535;
            src = seg == 0 ? Wq : seg == 1 ? Wk : seg == 2 ? Wv : Wo;
            dst = seg == 0 ? wqb : seg == 1 ? wkb : seg == 2 ? wvb : wob;
        }
        float4 v = ((const float4*)src)[off];
        ushort4 o;
        o.x = f2bf(v.x); o.y = f2bf(v.y); o.z = f2bf(v.z); o.w = f2bf(v.w);
        ((ushort4*)dst)[off] = o;
    } else {
        int jb = i - 1310720;                      // 0..2047
        int4 mv = ((const int4*)mask)[jb];
        float4 bo;
        bo.x = (mv.x == 1) ? 0.f : NEGB;
        bo.y = (mv.y == 1) ? 0.f : NEGB;
        bo.z = (mv.z == 1) ? 0.f : NEGB;
        bo.w = (mv.w == 1) ? 0.f : NEGB;
        ((float4*)biasf)[jb] = bo;
    }
}

// ---------------- fused QKV GEMM: C = x @ [Wq;Wk;Wv]^T ----------------------
// XCD-aware block swizzle (T1): the 12 N-blocks sharing one 128KB A-panel
// previously round-robined across all 8 XCD L2s (dispatch%8), replicating A
// and churning each L2 through the full 8MB A. Remap so XCD c owns all 12
// N-blocks of panel rows y == c (mod 8): per-XCD working set = 8 panels
// (1MB) + W (1.5MB) < 4MB L2. Bijection: flat = y'*12+x' -> c=flat&7,
// s=flat>>3, x=s%12, y=(s/12)*8+c.
// K layout (per 64-key tile, 4096 u16): chunk(ntk*2+g)*512 + (quadd*16+key&15)*8 + jd
//   where ntk = 16-key group, g = d>>5, quadd = (d>>3)&3, jd = d&7.
// V layout (per 64-key tile, 4096 u16): pair*2048 + ct*512 + (keyquad*16+dl)*8 + s*4 + jj
//   where pair = (key>>5)&1, s = (key>>4)&1, keyquad = (key>>2)&3, jj = key&3,
//   ct = (d>>4)&3, dl = d&15.  One bf16x8 at lane*8 is a ready PV B-fragment.
__global__ __launch_bounds__(256, 3) void gemm_qkv_fused(
    const u16* __restrict__ A, const u16* __restrict__ Wcat,
    u16* __restrict__ Oq, u16* __restrict__ Okf, u16* __restrict__ Ovf)
{
    __shared__ u16 ldsA[8192];   // 128 rows x 64, chunk i (1KB) = rows 8i..8i+7
    __shared__ u16 ldsB[8192];

    int flat = blockIdx.y * 12 + blockIdx.x;   // HW dispatch index (x fastest)
    int c  = flat & 7, s = flat >> 3;          // XCD = flat % 8 heuristic
    int bx = s % 12;
    int by = (s / 12) * 8 + c;                 // 96 blocks/XCD, 8 A-panels each
    int n0 = bx * 128;   // 0..1535
    int m0 = by * 128;
    int tid = threadIdx.x;
    int w = tid >> 6, lane = tid & 63, quad = lane >> 4, l16 = lane & 15;
    int mo = (w & 1) * 64, no = (w >> 1) * 64;
    int l7 = l16 & 7;

    int sr = lane >> 3, sc = lane & 7, gc = sc ^ sr;   // staging row/chunk-swz
    const u16* gA0 = A    + (long)(m0 + sr) * DIM + gc * 8;
    const u16* gB0 = Wcat + (long)(n0 + sr) * DIM + gc * 8;

    floatx4 acc[4][4];
    #pragma unroll
    for (int mt = 0; mt < 4; mt++)
        #pragma unroll
        for (int nt = 0; nt < 4; nt++) acc[mt][nt] = (floatx4){0.f,0.f,0.f,0.f};

    for (int k0 = 0; k0 < DIM; k0 += 64) {
        #pragma unroll
        for (int i = 0; i < 4; i++) {
            int ch = w * 4 + i;
            gload16(gA0 + (long)ch * 8 * DIM + k0, &ldsA[ch * 512]);
            gload16(gB0 + (long)ch * 8 * DIM + k0, &ldsB[ch * 512]);
        }
        __syncthreads();

        #pragma unroll
        for (int kc = 0; kc < 2; kc++) {
            int swz = ((kc * 4 + quad) ^ l7) * 8;
            bf16x8 af[4], bf[4];
            #pragma unroll
            for (int t4 = 0; t4 < 4; t4++) {
                af[t4] = *(const bf16x8*)&ldsA[(mo + t4*16 + l16) * 64 + swz];
                bf[t4] = *(const bf16x8*)&ldsB[(no + t4*16 + l16) * 64 + swz];
            }
            #pragma unroll
            for (int mt = 0; mt < 4; mt++)
                #pragma unroll
                for (int nt = 0; nt < 4; nt++)
                    acc[mt][nt] = __builtin_amdgcn_mfma_f32_16x16x32_bf16(
                        af[mt], bf[nt], acc[mt][nt], 0, 0, 0);
        }
        __syncthreads();
    }

    int seg = n0 >> 9;    // block-uniform: 0=Q 1=K 2=V
    if (seg == 0) {
        #pragma unroll
        for (int mt = 0; mt < 4; mt++)
            #pragma unroll
            for (int nt = 0; nt < 4; nt++)
                #pragma unroll
                for (int r = 0; r < 4; r++) {
                    int row = m0 + mo + mt*16 + quad*4 + r;      // b*SEQ+n
                    int col9 = (n0 + no + nt*16 + l16) & 511;    // h*64+d
                    int b = row >> 11, n = row & 2047, h = col9 >> 6, d = col9 & 63;
                    Oq[(((long)(b * HEADS + h) * SEQ + n) << 6) + d] = f2bf(acc[mt][nt][r]);
                }
    } else if (seg == 1) {
        #pragma unroll
        for (int mt = 0; mt < 4; mt++)
            #pragma unroll
            for (int nt = 0; nt < 4; nt++)
                #pragma unroll
                for (int r = 0; r < 4; r++) {
                    int row = m0 + mo + mt*16 + quad*4 + r;
                    int col9 = (n0 + no + nt*16 + l16) & 511;
                    int b = row >> 11, keyn = row & 2047, h = col9 >> 6, dd = col9 & 63;
                    int kt = keyn >> 6, ntk = (keyn >> 4) & 3, l16k = keyn & 15;
                    int g = dd >> 5, quadk = (dd >> 3) & 3, j = dd & 7;
                    long offv = ((long)((b*HEADS + h)*32 + kt) << 12)
                              + ((ntk*2 + g) << 9) + ((quadk*16 + l16k) << 3) + j;
                    Okf[offv] = f2bf(acc[mt][nt][r] * SCL2E);
                }
    } else {
        // V in PV-B-fragment order (see header comment). keyn = base + r with
        // base%4==0, so jj = r and the 4 acc values are one ushort4.
        #pragma unroll
        for (int mt = 0; mt < 4; mt++)
            #pragma unroll
            for (int nt = 0; nt < 4; nt++) {
                int rowb = m0 + mo + mt*16 + quad*4;
                int col9 = (n0 + no + nt*16 + l16) & 511;
                int b = rowb >> 11, keyn = rowb & 2047, h = col9 >> 6;
                int tile = (keyn >> 6) & 31;
                // pair = mt>>1, s = mt&1, keyquad = quad, jj = r
                // ct = nt ((n0+no)%64==0), dl = l16
                long offv = ((long)((b*HEADS + h)*32 + tile) << 12)
                          + ((long)(mt >> 1) << 11) + (nt << 9)
                          + ((quad*16 + l16) << 3) + ((mt & 1) << 2);
                ushort4 st;
                st.x = f2bf(acc[mt][nt][0]); st.y = f2bf(acc[mt][nt][1]);
                st.z = f2bf(acc[mt][nt][2]); st.w = f2bf(acc[mt][nt][3]);
                *(ushort4*)&Ovf[offv] = st;
            }
    }
}

// ---------------- flash attention: key-split, register-direct ---------------
// v4 VERBATIM (best measured: 53.2us). The bracket around it is complete:
// wide phases +4.7, QK rotation spilled, 3-blk squeeze spilled x2, bias-as-C
// +1.3, lsum-on-VALU +1.2. Local optimum at 2 blk/CU; do not perturb.
__global__ __launch_bounds__(256, 2) void flash_attn(
    const u16* __restrict__ Q, const u16* __restrict__ Kf,
    const u16* __restrict__ Vf, const float* __restrict__ biasf,
    u16* __restrict__ ctx)
{
    __shared__ float red[4352];   // [0,4096) O slots (1024 floatx4), [4096,4352) lsum

    int bx = blockIdx.x;
    // decode XCD swizzle: bx = (g&7) + 8*((g>>3)*32 + i), g = b*8+h, i = q-block
    int cx = bx & 7, sx = bx >> 3;
    int gg = ((sx >> 5) << 3) | cx;
    int qi = sx & 31;
    int q0 = qi * 64;
    int h  = gg & 7;
    int b  = gg >> 3;
    int bh = b * HEADS + h;

    int tid = threadIdx.x;
    int w = tid >> 6, lane = tid & 63, quad = lane >> 4, l16 = lane & 15;

    // Q B-frags for all 4 q-tiles (wave needs all 64 q)
    bf16x8 qb[4][2];
    #pragma unroll
    for (int nt = 0; nt < 4; nt++) {
        const u16* qp = Q + ((long)bh * SEQ + q0 + nt*16 + l16) * HD + quad * 8;
        qb[nt][0] = *(const bf16x8*)(qp);
        qb[nt][1] = *(const bf16x8*)(qp + 32);
    }

    // wave's 32-key slice per iteration: keys = it*128 + w*32 + s*16 + quad*4 + j
    // K: it*8192 + w*2048 + s*1024 + g*512 ; V: it*8192 + w*2048 + ct*512
    const u16* Kw = Kf + ((long)bh << 17) + w*2048 + lane*8;
    const u16* Vw = Vf + ((long)bh << 17) + w*2048 + lane*8;
    const float* bw = biasf + b * SEQ + w*32 + quad*4;          // + it*128 (+16 for s=1)

    // ones-column B operand (K=32): 1.0 only for n == 0 (lanes l16==0), all k
    short one_s = (l16 == 0) ? (short)0x3F80 : (short)0;
    bf16x8 ones8 = { one_s, one_s, one_s, one_s, one_s, one_s, one_s, one_s };

    // rolling preload: it = 0
    bf16x8 k00 = *(const bf16x8*)(Kw);
    bf16x8 k01 = *(const bf16x8*)(Kw + 512);
    bf16x8 k10 = *(const bf16x8*)(Kw + 1024);
    bf16x8 k11 = *(const bf16x8*)(Kw + 1536);
    bf16x8 vb0 = *(const bf16x8*)(Vw);
    bf16x8 vb1 = *(const bf16x8*)(Vw + 512);
    bf16x8 vb2 = *(const bf16x8*)(Vw + 1024);
    bf16x8 vb3 = *(const bf16x8*)(Vw + 1536);
    float4 bv0 = *(const float4*)(bw);
    float4 bv1 = *(const float4*)(bw + 16);

    floatx4 o[4][4];
    floatx4 o5[4];
    #pragma unroll
    for (int nt = 0; nt < 4; nt++) {
        #pragma unroll
        for (int ct = 0; ct < 4; ct++) o[nt][ct] = (floatx4){0.f,0.f,0.f,0.f};
        o5[nt] = (floatx4){0.f,0.f,0.f,0.f};
    }

    #pragma unroll 2
    for (int it = 0; it < 16; it++) {
        // prefetch next iteration into fresh registers (compiler emits vmcnt(N))
        bf16x8 k00n=k00, k01n=k01, k10n=k10, k11n=k11;
        bf16x8 vb0n=vb0, vb1n=vb1, vb2n=vb2, vb3n=vb3;
        float4 bv0n=bv0, bv1n=bv1;
        if (it < 15) {
            const u16* kp = Kw + (long)(it+1)*8192;
            const u16* vp = Vw + (long)(it+1)*8192;
            k00n = *(const bf16x8*)(kp);
            k01n = *(const bf16x8*)(kp + 512);
            k10n = *(const bf16x8*)(kp + 1024);
            k11n = *(const bf16x8*)(kp + 1536);
            vb0n = *(const bf16x8*)(vp);
            vb1n = *(const bf16x8*)(vp + 512);
            vb2n = *(const bf16x8*)(vp + 1024);
            vb3n = *(const bf16x8*)(vp + 1536);
            bv0n = *(const float4*)(bw + (it+1)*128);
            bv1n = *(const float4*)(bw + (it+1)*128 + 16);
        }

        #pragma unroll
        for (int nt = 0; nt < 4; nt++) {
            // S^T[16key][16q] for both 16-key groups (C-init with bias)
            floatx4 s0, s1;
            s0[0] = bv0.x; s0[1] = bv0.y; s0[2] = bv0.z; s0[3] = bv0.w;
            s1[0] = bv1.x; s1[1] = bv1.y; s1[2] = bv1.z; s1[3] = bv1.w;
            __builtin_amdgcn_s_setprio(1);
            s0 = __builtin_amdgcn_mfma_f32_16x16x32_bf16(k00, qb[nt][0], s0, 0, 0, 0);
            s0 = __builtin_amdgcn_mfma_f32_16x16x32_bf16(k01, qb[nt][1], s0, 0, 0, 0);
            s1 = __builtin_amdgcn_mfma_f32_16x16x32_bf16(k10, qb[nt][0], s1, 0, 0, 0);
            s1 = __builtin_amdgcn_mfma_f32_16x16x32_bf16(k11, qb[nt][1], s1, 0, 0, 0);
            __builtin_amdgcn_s_setprio(0);
            float p0 = fexp2(s0[0]);
            float p1 = fexp2(s0[1]);
            float p2 = fexp2(s0[2]);
            float p3 = fexp2(s0[3]);
            float p4 = fexp2(s1[0]);
            float p5 = fexp2(s1[1]);
            float p6 = fexp2(s1[2]);
            float p7 = fexp2(s1[3]);
            // bf16x8 A-fragment: m=l16 (q), k=quad*8+j; j0-3 group0, j4-7 group1
            union { bf16x8 v; unsigned u[4]; } pu;
            pu.u[0] = pack2bf(p0, p1);
            pu.u[1] = pack2bf(p2, p3);
            pu.u[2] = pack2bf(p4, p5);
            pu.u[3] = pack2bf(p6, p7);
            __builtin_amdgcn_s_setprio(1);
            o[nt][0] = __builtin_amdgcn_mfma_f32_16x16x32_bf16(pu.v, vb0, o[nt][0], 0, 0, 0);
            o[nt][1] = __builtin_amdgcn_mfma_f32_16x16x32_bf16(pu.v, vb1, o[nt][1], 0, 0, 0);
            o[nt][2] = __builtin_amdgcn_mfma_f32_16x16x32_bf16(pu.v, vb2, o[nt][2], 0, 0, 0);
            o[nt][3] = __builtin_amdgcn_mfma_f32_16x16x32_bf16(pu.v, vb3, o[nt][3], 0, 0, 0);
            // denominator on the matrix pipe (rows q=quad*4+r at col l16==0)
            o5[nt] = __builtin_amdgcn_mfma_f32_16x16x32_bf16(pu.v, ones8, o5[nt], 0, 0, 0);
            __builtin_amdgcn_s_setprio(0);
        }

        k00 = k00n; k01 = k01n; k10 = k10n; k11 = k11n;
        vb0 = vb0n; vb1 = vb1n; vb2 = vb2n; vb3 = vb3n;
        bv0 = bv0n; bv1 = bv1n;
    }

    __syncthreads();
    float* ldsf = red;
    floatx4* ldsv = (floatx4*)red;

    // publish per-(wave, q) partial denominators from lanes l16==0
    if (l16 == 0) {
        #pragma unroll
        for (int nt = 0; nt < 4; nt++)
            #pragma unroll
            for (int r = 0; r < 4; r++)
                ldsf[4096 + w*64 + nt*16 + quad*4 + r] = o5[nt][r];
    }
    __syncthreads();

    // O rotation: 3 rounds; wave w ends owning full O for q-tile nt==w
    #pragma unroll
    for (int i2 = 1; i2 < 4; i2++) {
        int tslot = (w + i2) & 3;          // wave-uniform
        #pragma unroll
        for (int nt = 0; nt < 4; nt++)
            if (nt == tslot) {
                #pragma unroll
                for (int ct = 0; ct < 4; ct++)
                    ldsv[nt*256 + ct*64 + lane] = o[nt][ct];
            }
        __syncthreads();
        #pragma unroll
        for (int nt = 0; nt < 4; nt++)
            if (nt == w) {
                #pragma unroll
                for (int ct = 0; ct < 4; ct++) {
                    floatx4 v = ldsv[nt*256 + ct*64 + lane];
                    o[nt][ct] += v;
                }
            }
        __syncthreads();
    }

    // epilogue: wave w owns q = q0 + w*16 + quad*4 + r; d = ct*16 + l16
    #pragma unroll
    for (int nt = 0; nt < 4; nt++) {
        if (nt != w) continue;            // wave-uniform
        float inv[4];
        #pragma unroll
        for (int r = 0; r < 4; r++) {
            int q = w*16 + quad*4 + r;
            float sden = ldsf[4096 + q] + ldsf[4096 + 64 + q]
                       + ldsf[4096 + 128 + q] + ldsf[4096 + 192 + q];
            inv[r] = 1.0f / sden;
        }
        #pragma unroll
        for (int ct = 0; ct < 4; ct++) {
            int col = h * HD + ct*16 + l16;
            long rb = (long)(b * SEQ + q0 + w*16 + quad*4);
            #pragma unroll
            for (int r = 0; r < 4; r++)
                ctx[(rb + r) * DIM + col] = f2bf(o[nt][ct][r] * inv[r]);
        }
    }
}

// ---------------- output projection: 64x128 tile, 512 blocks (2/CU) ---------
// XCD swizzle (T1): XCD c owns m-rows y == c (mod 8); per-XCD working set =
// 16 ctx-panels (1MB) + wob (0.5MB) < 4MB L2.
__global__ __launch_bounds__(256, 4) void gemm_proj(
    const u16* __restrict__ A, const u16* __restrict__ Bt,
    float* __restrict__ Out)
{
    __shared__ u16 ldsA[4096];   // 64 x 64
    __shared__ u16 ldsB[8192];   // 128 x 64

    int flat = blockIdx.y * 4 + blockIdx.x;   // HW dispatch index (x fastest)
    int c = flat & 7, s = flat >> 3;          // XCD = flat % 8 heuristic
    int bx = s & 3;
    int by = (s >> 2) * 8 + c;                // 64 blocks/XCD, 16 panels each
    int n0 = bx * 128;
    int m0 = by * 64;
    int tid = threadIdx.x;
    int w = tid >> 6, lane = tid & 63, quad = lane >> 4, l16 = lane & 15;
    int l7 = l16 & 7;

    int sr = lane >> 3, sc = lane & 7, gc = sc ^ sr;
    const u16* gA0 = A  + (long)(m0 + sr) * DIM + gc * 8;
    const u16* gB0 = Bt + (long)(n0 + sr) * DIM + gc * 8;

    floatx4 acc[8];
    #pragma unroll
    for (int nt = 0; nt < 8; nt++) acc[nt] = (floatx4){0.f,0.f,0.f,0.f};

    for (int k0 = 0; k0 < DIM; k0 += 64) {
        gload16(gA0 + (long)(2*w)   * 8 * DIM + k0, &ldsA[(2*w)   * 512]);
        gload16(gA0 + (long)(2*w+1) * 8 * DIM + k0, &ldsA[(2*w+1) * 512]);
        #pragma unroll
        for (int i = 0; i < 4; i++)
            gload16(gB0 + (long)(4*w+i) * 8 * DIM + k0, &ldsB[(4*w+i) * 512]);
        __syncthreads();

        #pragma unroll
        for (int kc = 0; kc < 2; kc++) {
            int swz = ((kc * 4 + quad) ^ l7) * 8;
            bf16x8 af = *(const bf16x8*)&ldsA[(w*16 + l16) * 64 + swz];
            #pragma unroll
            for (int nt = 0; nt < 8; nt++) {
                bf16x8 bfv = *(const bf16x8*)&ldsB[(nt*16 + l16) * 64 + swz];
                acc[nt] = __builtin_amdgcn_mfma_f32_16x16x32_bf16(
                    af, bfv, acc[nt], 0, 0, 0);
            }
        }
        __syncthreads();
    }

    #pragma unroll
    for (int nt = 0; nt < 8; nt++)
        #pragma unroll
        for (int r = 0; r < 4; r++) {
            int row = m0 + w*16 + quad*4 + r;
            int col = n0 + nt*16 + l16;
            Out[(long)row * DIM + col] = acc[nt][r];
        }
}

extern "C" void kernel_launch(void* const* d_in, const int* in_sizes, int n_in,
                              void* d_out, int out_size, void* d_ws, size_t ws_size,
                              hipStream_t stream) {
    const float* x  = (const float*)d_in[0];
    const float* Wq = (const float*)d_in[1];
    const float* Wk = (const float*)d_in[2];
    const float* Wv = (const float*)d_in[3];
    const float* Wo = (const float*)d_in[4];
    const int* mask = (const int*)d_in[5];
    float* out = (float*)d_out;

    char* ws = (char*)d_ws;
    size_t off = 0;
    u16* xb  = (u16*)(ws + off); off += (size_t)ROWS * DIM * 2;
    u16* wqb = (u16*)(ws + off); off += (size_t)DIM * DIM * 2;   // wq/wk/wv contiguous = Wcat
    u16* wkb = (u16*)(ws + off); off += (size_t)DIM * DIM * 2;
    u16* wvb = (u16*)(ws + off); off += (size_t)DIM * DIM * 2;
    u16* wob = (u16*)(ws + off); off += (size_t)DIM * DIM * 2;
    u16* Qh  = (u16*)(ws + off); off += (size_t)ROWS * DIM * 2;
    u16* Kfr = (u16*)(ws + off); off += (size_t)ROWS * DIM * 2;
    u16* Vfr = (u16*)(ws + off); off += (size_t)ROWS * DIM * 2;
    u16* ctx = (u16*)(ws + off); off += (size_t)ROWS * DIM * 2;
    float* biasf = (float*)(ws + off); off += (size_t)BS * SEQ * 4;

    convert_all<<<5128, 256, 0, stream>>>(x, Wq, Wk, Wv, Wo, mask,
                                          xb, wqb, wkb, wvb, wob, biasf);
    gemm_qkv_fused<<<dim3(12, 64), 256, 0, stream>>>(xb, wqb, Qh, Kfr, Vfr);
    flash_attn<<<BS * HEADS * (SEQ / 64), 256, 0, stream>>>(Qh, Kfr, Vfr, biasf, ctx);
    gemm_proj<<<dim3(4, 128), 256, 0, stream>>>(ctx, wob, out);

    (void)in_sizes; (void)n_in; (void)out_size; (void)ws_size;
}

// Round 10
// 153.483 us; speedup vs baseline: 1.0237x; 1.0237x over previous
//
#include <hip/hip_runtime.h>
#include <hip/hip_bf16.h>

#define BS 4
#define SEQ 2048
#define DIM 512
#define HEADS 8
#define HD 64
#define ROWS (BS*SEQ)   // 8192
// (1/sqrt(64)) * log2(e) folded into K at projection time
#define SCL2E 0.1803368801111244f
#define NEGB (-1.4426950408889634e6f)   // -1e6 * log2(e)

typedef __attribute__((ext_vector_type(8))) short bf16x8;
typedef __attribute__((ext_vector_type(4))) short bf16x4;
typedef __attribute__((ext_vector_type(4))) float floatx4;
typedef unsigned short u16;
typedef unsigned int u32;

__device__ __forceinline__ u16 f2bf(float f) {
    union { float f; unsigned u; } v; v.f = f;
    unsigned r = v.u + 0x7fff + ((v.u >> 16) & 1);
    return (u16)(r >> 16);
}

__device__ __forceinline__ unsigned pack2bf(float a, float b) {
#if __has_builtin(__builtin_amdgcn_cvt_pk_bf16_f32)
    typedef __attribute__((ext_vector_type(2))) __bf16 bf2;
    union { bf2 v; unsigned u; } cv;
    cv.v = __builtin_amdgcn_cvt_pk_bf16_f32(a, b);
    return cv.u;
#else
    return (unsigned)f2bf(a) | ((unsigned)f2bf(b) << 16);
#endif
}

__device__ __forceinline__ float fexp2(float x) {
#if __has_builtin(__builtin_amdgcn_exp2f)
    return __builtin_amdgcn_exp2f(x);     // raw v_exp_f32
#else
    return __expf(x * 0.6931471805599453f);
#endif
}

// async global->LDS, 16B per lane. g is PER-LANE global addr, l is wave-uniform.
__device__ __forceinline__ void gload16(const u16* g, u16* l) {
    __builtin_amdgcn_global_load_lds(
        (const __attribute__((address_space(1))) u32*)g,
        (__attribute__((address_space(3))) u32*)l, 16, 0, 0);
}

// ---------------- fp32 -> bf16 conversion; mask -> exp2-domain bias ---------
__global__ __launch_bounds__(256) void convert_all(
    const float* __restrict__ x, const float* __restrict__ Wq,
    const float* __restrict__ Wk, const float* __restrict__ Wv,
    const float* __restrict__ Wo, const int* __restrict__ mask,
    u16* __restrict__ xb, u16* __restrict__ wqb,
    u16* __restrict__ wkb, u16* __restrict__ wvb,
    u16* __restrict__ wob, float* __restrict__ biasf)
{
    int i = blockIdx.x * 256 + threadIdx.x;
    if (i < 1048576 + 262144) {
        const float* src; u16* dst; int off;
        if (i < 1048576) { src = x; dst = xb; off = i; }
        else {
            int j = i - 1048576; int seg = j >> 16; off = j & 65535;
            src = seg == 0 ? Wq : seg == 1 ? Wk : seg == 2 ? Wv : Wo;
            dst = seg == 0 ? wqb : seg == 1 ? wkb : seg == 2 ? wvb : wob;
        }
        float4 v = ((const float4*)src)[off];
        ushort4 o;
        o.x = f2bf(v.x); o.y = f2bf(v.y); o.z = f2bf(v.z); o.w = f2bf(v.w);
        ((ushort4*)dst)[off] = o;
    } else {
        int jb = i - 1310720;                      // 0..2047
        int4 mv = ((const int4*)mask)[jb];
        float4 bo;
        bo.x = (mv.x == 1) ? 0.f : NEGB;
        bo.y = (mv.y == 1) ? 0.f : NEGB;
        bo.z = (mv.z == 1) ? 0.f : NEGB;
        bo.w = (mv.w == 1) ? 0.f : NEGB;
        ((float4*)biasf)[jb] = bo;
    }
}

// ---------------- fused QKV GEMM: C = x @ [Wq;Wk;Wv]^T ----------------------
// XCD-aware block swizzle (T1): measured neutral (R9) but theoretically sound
// and harmless; kept. Bijection: flat = y'*12+x' -> c=flat&7, s=flat>>3,
// x=s%12, y=(s/12)*8+c.
// K layout (per 64-key tile, 4096 u16): chunk(ntk*2+g)*512 + (quadd*16+key&15)*8 + jd
//   where ntk = 16-key group, g = d>>5, quadd = (d>>3)&3, jd = d&7.
// V layout (per 64-key tile, 4096 u16): pair*2048 + ct*512 + (keyquad*16+dl)*8 + s*4 + jj
//   where pair = (key>>5)&1, s = (key>>4)&1, keyquad = (key>>2)&3, jj = key&3,
//   ct = (d>>4)&3, dl = d&15.  One bf16x8 at lane*8 is a ready PV B-fragment.
__global__ __launch_bounds__(256, 3) void gemm_qkv_fused(
    const u16* __restrict__ A, const u16* __restrict__ Wcat,
    u16* __restrict__ Oq, u16* __restrict__ Okf, u16* __restrict__ Ovf)
{
    __shared__ u16 ldsA[8192];   // 128 rows x 64, chunk i (1KB) = rows 8i..8i+7
    __shared__ u16 ldsB[8192];

    int flat = blockIdx.y * 12 + blockIdx.x;   // HW dispatch index (x fastest)
    int c  = flat & 7, s = flat >> 3;          // XCD = flat % 8 heuristic
    int bx = s % 12;
    int by = (s / 12) * 8 + c;                 // 96 blocks/XCD, 8 A-panels each
    int n0 = bx * 128;   // 0..1535
    int m0 = by * 128;
    int tid = threadIdx.x;
    int w = tid >> 6, lane = tid & 63, quad = lane >> 4, l16 = lane & 15;
    int mo = (w & 1) * 64, no = (w >> 1) * 64;
    int l7 = l16 & 7;

    int sr = lane >> 3, sc = lane & 7, gc = sc ^ sr;   // staging row/chunk-swz
    const u16* gA0 = A    + (long)(m0 + sr) * DIM + gc * 8;
    const u16* gB0 = Wcat + (long)(n0 + sr) * DIM + gc * 8;

    floatx4 acc[4][4];
    #pragma unroll
    for (int mt = 0; mt < 4; mt++)
        #pragma unroll
        for (int nt = 0; nt < 4; nt++) acc[mt][nt] = (floatx4){0.f,0.f,0.f,0.f};

    for (int k0 = 0; k0 < DIM; k0 += 64) {
        #pragma unroll
        for (int i = 0; i < 4; i++) {
            int ch = w * 4 + i;
            gload16(gA0 + (long)ch * 8 * DIM + k0, &ldsA[ch * 512]);
            gload16(gB0 + (long)ch * 8 * DIM + k0, &ldsB[ch * 512]);
        }
        __syncthreads();

        #pragma unroll
        for (int kc = 0; kc < 2; kc++) {
            int swz = ((kc * 4 + quad) ^ l7) * 8;
            bf16x8 af[4], bf[4];
            #pragma unroll
            for (int t4 = 0; t4 < 4; t4++) {
                af[t4] = *(const bf16x8*)&ldsA[(mo + t4*16 + l16) * 64 + swz];
                bf[t4] = *(const bf16x8*)&ldsB[(no + t4*16 + l16) * 64 + swz];
            }
            #pragma unroll
            for (int mt = 0; mt < 4; mt++)
                #pragma unroll
                for (int nt = 0; nt < 4; nt++)
                    acc[mt][nt] = __builtin_amdgcn_mfma_f32_16x16x32_bf16(
                        af[mt], bf[nt], acc[mt][nt], 0, 0, 0);
        }
        __syncthreads();
    }

    int seg = n0 >> 9;    // block-uniform: 0=Q 1=K 2=V
    if (seg == 0) {
        #pragma unroll
        for (int mt = 0; mt < 4; mt++)
            #pragma unroll
            for (int nt = 0; nt < 4; nt++)
                #pragma unroll
                for (int r = 0; r < 4; r++) {
                    int row = m0 + mo + mt*16 + quad*4 + r;      // b*SEQ+n
                    int col9 = (n0 + no + nt*16 + l16) & 511;    // h*64+d
                    int b = row >> 11, n = row & 2047, h = col9 >> 6, d = col9 & 63;
                    Oq[(((long)(b * HEADS + h) * SEQ + n) << 6) + d] = f2bf(acc[mt][nt][r]);
                }
    } else if (seg == 1) {
        #pragma unroll
        for (int mt = 0; mt < 4; mt++)
            #pragma unroll
            for (int nt = 0; nt < 4; nt++)
                #pragma unroll
                for (int r = 0; r < 4; r++) {
                    int row = m0 + mo + mt*16 + quad*4 + r;
                    int col9 = (n0 + no + nt*16 + l16) & 511;
                    int b = row >> 11, keyn = row & 2047, h = col9 >> 6, dd = col9 & 63;
                    int kt = keyn >> 6, ntk = (keyn >> 4) & 3, l16k = keyn & 15;
                    int g = dd >> 5, quadk = (dd >> 3) & 3, j = dd & 7;
                    long offv = ((long)((b*HEADS + h)*32 + kt) << 12)
                              + ((ntk*2 + g) << 9) + ((quadk*16 + l16k) << 3) + j;
                    Okf[offv] = f2bf(acc[mt][nt][r] * SCL2E);
                }
    } else {
        // V in PV-B-fragment order (see header comment). keyn = base + r with
        // base%4==0, so jj = r and the 4 acc values are one ushort4.
        #pragma unroll
        for (int mt = 0; mt < 4; mt++)
            #pragma unroll
            for (int nt = 0; nt < 4; nt++) {
                int rowb = m0 + mo + mt*16 + quad*4;
                int col9 = (n0 + no + nt*16 + l16) & 511;
                int b = rowb >> 11, keyn = rowb & 2047, h = col9 >> 6;
                int tile = (keyn >> 6) & 31;
                // pair = mt>>1, s = mt&1, keyquad = quad, jj = r
                // ct = nt ((n0+no)%64==0), dl = l16
                long offv = ((long)((b*HEADS + h)*32 + tile) << 12)
                          + ((long)(mt >> 1) << 11) + (nt << 9)
                          + ((quad*16 + l16) << 3) + ((mt & 1) << 2);
                ushort4 st;
                st.x = f2bf(acc[mt][nt][0]); st.y = f2bf(acc[mt][nt][1]);
                st.z = f2bf(acc[mt][nt][2]); st.w = f2bf(acc[mt][nt][3]);
                *(ushort4*)&Ovf[offv] = st;
            }
    }
}

// ---------------- flash attention: key-split, register-direct ---------------
// v4 VERBATIM (best measured: 52.5-53.2us). The bracket around it is complete:
// wide phases +4.7, QK rotation spilled, 3-blk squeeze spilled x2, bias-as-C
// +1.3, lsum-on-VALU +1.2. Local optimum at 2 blk/CU; do not perturb.
__global__ __launch_bounds__(256, 2) void flash_attn(
    const u16* __restrict__ Q, const u16* __restrict__ Kf,
    const u16* __restrict__ Vf, const float* __restrict__ biasf,
    u16* __restrict__ ctx)
{
    __shared__ float red[4352];   // [0,4096) O slots (1024 floatx4), [4096,4352) lsum

    int bx = blockIdx.x;
    // decode XCD swizzle: bx = (g&7) + 8*((g>>3)*32 + i), g = b*8+h, i = q-block
    int cx = bx & 7, sx = bx >> 3;
    int gg = ((sx >> 5) << 3) | cx;
    int qi = sx & 31;
    int q0 = qi * 64;
    int h  = gg & 7;
    int b  = gg >> 3;
    int bh = b * HEADS + h;

    int tid = threadIdx.x;
    int w = tid >> 6, lane = tid & 63, quad = lane >> 4, l16 = lane & 15;

    // Q B-frags for all 4 q-tiles (wave needs all 64 q)
    bf16x8 qb[4][2];
    #pragma unroll
    for (int nt = 0; nt < 4; nt++) {
        const u16* qp = Q + ((long)bh * SEQ + q0 + nt*16 + l16) * HD + quad * 8;
        qb[nt][0] = *(const bf16x8*)(qp);
        qb[nt][1] = *(const bf16x8*)(qp + 32);
    }

    // wave's 32-key slice per iteration: keys = it*128 + w*32 + s*16 + quad*4 + j
    // K: it*8192 + w*2048 + s*1024 + g*512 ; V: it*8192 + w*2048 + ct*512
    const u16* Kw = Kf + ((long)bh << 17) + w*2048 + lane*8;
    const u16* Vw = Vf + ((long)bh << 17) + w*2048 + lane*8;
    const float* bw = biasf + b * SEQ + w*32 + quad*4;          // + it*128 (+16 for s=1)

    // ones-column B operand (K=32): 1.0 only for n == 0 (lanes l16==0), all k
    short one_s = (l16 == 0) ? (short)0x3F80 : (short)0;
    bf16x8 ones8 = { one_s, one_s, one_s, one_s, one_s, one_s, one_s, one_s };

    // rolling preload: it = 0
    bf16x8 k00 = *(const bf16x8*)(Kw);
    bf16x8 k01 = *(const bf16x8*)(Kw + 512);
    bf16x8 k10 = *(const bf16x8*)(Kw + 1024);
    bf16x8 k11 = *(const bf16x8*)(Kw + 1536);
    bf16x8 vb0 = *(const bf16x8*)(Vw);
    bf16x8 vb1 = *(const bf16x8*)(Vw + 512);
    bf16x8 vb2 = *(const bf16x8*)(Vw + 1024);
    bf16x8 vb3 = *(const bf16x8*)(Vw + 1536);
    float4 bv0 = *(const float4*)(bw);
    float4 bv1 = *(const float4*)(bw + 16);

    floatx4 o[4][4];
    floatx4 o5[4];
    #pragma unroll
    for (int nt = 0; nt < 4; nt++) {
        #pragma unroll
        for (int ct = 0; ct < 4; ct++) o[nt][ct] = (floatx4){0.f,0.f,0.f,0.f};
        o5[nt] = (floatx4){0.f,0.f,0.f,0.f};
    }

    #pragma unroll 2
    for (int it = 0; it < 16; it++) {
        // prefetch next iteration into fresh registers (compiler emits vmcnt(N))
        bf16x8 k00n=k00, k01n=k01, k10n=k10, k11n=k11;
        bf16x8 vb0n=vb0, vb1n=vb1, vb2n=vb2, vb3n=vb3;
        float4 bv0n=bv0, bv1n=bv1;
        if (it < 15) {
            const u16* kp = Kw + (long)(it+1)*8192;
            const u16* vp = Vw + (long)(it+1)*8192;
            k00n = *(const bf16x8*)(kp);
            k01n = *(const bf16x8*)(kp + 512);
            k10n = *(const bf16x8*)(kp + 1024);
            k11n = *(const bf16x8*)(kp + 1536);
            vb0n = *(const bf16x8*)(vp);
            vb1n = *(const bf16x8*)(vp + 512);
            vb2n = *(const bf16x8*)(vp + 1024);
            vb3n = *(const bf16x8*)(vp + 1536);
            bv0n = *(const float4*)(bw + (it+1)*128);
            bv1n = *(const float4*)(bw + (it+1)*128 + 16);
        }

        #pragma unroll
        for (int nt = 0; nt < 4; nt++) {
            // S^T[16key][16q] for both 16-key groups (C-init with bias)
            floatx4 s0, s1;
            s0[0] = bv0.x; s0[1] = bv0.y; s0[2] = bv0.z; s0[3] = bv0.w;
            s1[0] = bv1.x; s1[1] = bv1.y; s1[2] = bv1.z; s1[3] = bv1.w;
            __builtin_amdgcn_s_setprio(1);
            s0 = __builtin_amdgcn_mfma_f32_16x16x32_bf16(k00, qb[nt][0], s0, 0, 0, 0);
            s0 = __builtin_amdgcn_mfma_f32_16x16x32_bf16(k01, qb[nt][1], s0, 0, 0, 0);
            s1 = __builtin_amdgcn_mfma_f32_16x16x32_bf16(k10, qb[nt][0], s1, 0, 0, 0);
            s1 = __builtin_amdgcn_mfma_f32_16x16x32_bf16(k11, qb[nt][1], s1, 0, 0, 0);
            __builtin_amdgcn_s_setprio(0);
            float p0 = fexp2(s0[0]);
            float p1 = fexp2(s0[1]);
            float p2 = fexp2(s0[2]);
            float p3 = fexp2(s0[3]);
            float p4 = fexp2(s1[0]);
            float p5 = fexp2(s1[1]);
            float p6 = fexp2(s1[2]);
            float p7 = fexp2(s1[3]);
            // bf16x8 A-fragment: m=l16 (q), k=quad*8+j; j0-3 group0, j4-7 group1
            union { bf16x8 v; unsigned u[4]; } pu;
            pu.u[0] = pack2bf(p0, p1);
            pu.u[1] = pack2bf(p2, p3);
            pu.u[2] = pack2bf(p4, p5);
            pu.u[3] = pack2bf(p6, p7);
            __builtin_amdgcn_s_setprio(1);
            o[nt][0] = __builtin_amdgcn_mfma_f32_16x16x32_bf16(pu.v, vb0, o[nt][0], 0, 0, 0);
            o[nt][1] = __builtin_amdgcn_mfma_f32_16x16x32_bf16(pu.v, vb1, o[nt][1], 0, 0, 0);
            o[nt][2] = __builtin_amdgcn_mfma_f32_16x16x32_bf16(pu.v, vb2, o[nt][2], 0, 0, 0);
            o[nt][3] = __builtin_amdgcn_mfma_f32_16x16x32_bf16(pu.v, vb3, o[nt][3], 0, 0, 0);
            // denominator on the matrix pipe (rows q=quad*4+r at col l16==0)
            o5[nt] = __builtin_amdgcn_mfma_f32_16x16x32_bf16(pu.v, ones8, o5[nt], 0, 0, 0);
            __builtin_amdgcn_s_setprio(0);
        }

        k00 = k00n; k01 = k01n; k10 = k10n; k11 = k11n;
        vb0 = vb0n; vb1 = vb1n; vb2 = vb2n; vb3 = vb3n;
        bv0 = bv0n; bv1 = bv1n;
    }

    __syncthreads();
    float* ldsf = red;
    floatx4* ldsv = (floatx4*)red;

    // publish per-(wave, q) partial denominators from lanes l16==0
    if (l16 == 0) {
        #pragma unroll
        for (int nt = 0; nt < 4; nt++)
            #pragma unroll
            for (int r = 0; r < 4; r++)
                ldsf[4096 + w*64 + nt*16 + quad*4 + r] = o5[nt][r];
    }
    __syncthreads();

    // O rotation: 3 rounds; wave w ends owning full O for q-tile nt==w
    #pragma unroll
    for (int i2 = 1; i2 < 4; i2++) {
        int tslot = (w + i2) & 3;          // wave-uniform
        #pragma unroll
        for (int nt = 0; nt < 4; nt++)
            if (nt == tslot) {
                #pragma unroll
                for (int ct = 0; ct < 4; ct++)
                    ldsv[nt*256 + ct*64 + lane] = o[nt][ct];
            }
        __syncthreads();
        #pragma unroll
        for (int nt = 0; nt < 4; nt++)
            if (nt == w) {
                #pragma unroll
                for (int ct = 0; ct < 4; ct++) {
                    floatx4 v = ldsv[nt*256 + ct*64 + lane];
                    o[nt][ct] += v;
                }
            }
        __syncthreads();
    }

    // epilogue: wave w owns q = q0 + w*16 + quad*4 + r; d = ct*16 + l16
    #pragma unroll
    for (int nt = 0; nt < 4; nt++) {
        if (nt != w) continue;            // wave-uniform
        float inv[4];
        #pragma unroll
        for (int r = 0; r < 4; r++) {
            int q = w*16 + quad*4 + r;
            float sden = ldsf[4096 + q] + ldsf[4096 + 64 + q]
                       + ldsf[4096 + 128 + q] + ldsf[4096 + 192 + q];
            inv[r] = 1.0f / sden;
        }
        #pragma unroll
        for (int ct = 0; ct < 4; ct++) {
            int col = h * HD + ct*16 + l16;
            long rb = (long)(b * SEQ + q0 + w*16 + quad*4);
            #pragma unroll
            for (int r = 0; r < 4; r++)
                ctx[(rb + r) * DIM + col] = f2bf(o[nt][ct][r] * inv[r]);
        }
    }
}

// ---------------- output projection: 64x64 tile, 1024 blocks (4/CU) ---------
// v2: retiled from 64x128/512 blocks (2 blk/CU) to 64x64/1024 blocks (4/CU).
// Same total A/B traffic and MFMA count; per-thread staging drops 6->4
// gload16/K-step while resident waves double -> 2x latency-hiding TLP for
// the short (8-step) K-loop whose per-step stage-wait was exposed at 2/CU.
__global__ __launch_bounds__(256, 4) void gemm_proj(
    const u16* __restrict__ A, const u16* __restrict__ Bt,
    float* __restrict__ Out)
{
    __shared__ u16 ldsA[4096];   // 64 x 64
    __shared__ u16 ldsB[4096];   // 64 x 64

    int n0 = blockIdx.x * 64;    // 8 n-blocks
    int m0 = blockIdx.y * 64;    // 128 m-blocks
    int tid = threadIdx.x;
    int w = tid >> 6, lane = tid & 63, quad = lane >> 4, l16 = lane & 15;
    int l7 = l16 & 7;

    int sr = lane >> 3, sc = lane & 7, gc = sc ^ sr;
    const u16* gA0 = A  + (long)(m0 + sr) * DIM + gc * 8;
    const u16* gB0 = Bt + (long)(n0 + sr) * DIM + gc * 8;

    floatx4 acc[4];
    #pragma unroll
    for (int nt = 0; nt < 4; nt++) acc[nt] = (floatx4){0.f,0.f,0.f,0.f};

    for (int k0 = 0; k0 < DIM; k0 += 64) {
        #pragma unroll
        for (int i = 0; i < 2; i++) {
            int ch = 2*w + i;
            gload16(gA0 + (long)ch * 8 * DIM + k0, &ldsA[ch * 512]);
            gload16(gB0 + (long)ch * 8 * DIM + k0, &ldsB[ch * 512]);
        }
        __syncthreads();

        #pragma unroll
        for (int kc = 0; kc < 2; kc++) {
            int swz = ((kc * 4 + quad) ^ l7) * 8;
            bf16x8 af = *(const bf16x8*)&ldsA[(w*16 + l16) * 64 + swz];
            #pragma unroll
            for (int nt = 0; nt < 4; nt++) {
                bf16x8 bfv = *(const bf16x8*)&ldsB[(nt*16 + l16) * 64 + swz];
                acc[nt] = __builtin_amdgcn_mfma_f32_16x16x32_bf16(
                    af, bfv, acc[nt], 0, 0, 0);
            }
        }
        __syncthreads();
    }

    #pragma unroll
    for (int nt = 0; nt < 4; nt++)
        #pragma unroll
        for (int r = 0; r < 4; r++) {
            int row = m0 + w*16 + quad*4 + r;
            int col = n0 + nt*16 + l16;
            Out[(long)row * DIM + col] = acc[nt][r];
        }
}

extern "C" void kernel_launch(void* const* d_in, const int* in_sizes, int n_in,
                              void* d_out, int out_size, void* d_ws, size_t ws_size,
                              hipStream_t stream) {
    const float* x  = (const float*)d_in[0];
    const float* Wq = (const float*)d_in[1];
    const float* Wk = (const float*)d_in[2];
    const float* Wv = (const float*)d_in[3];
    const float* Wo = (const float*)d_in[4];
    const int* mask = (const int*)d_in[5];
    float* out = (float*)d_out;

    char* ws = (char*)d_ws;
    size_t off = 0;
    u16* xb  = (u16*)(ws + off); off += (size_t)ROWS * DIM * 2;
    u16* wqb = (u16*)(ws + off); off += (size_t)DIM * DIM * 2;   // wq/wk/wv contiguous = Wcat
    u16* wkb = (u16*)(ws + off); off += (size_t)DIM * DIM * 2;
    u16* wvb = (u16*)(ws + off); off += (size_t)DIM * DIM * 2;
    u16* wob = (u16*)(ws + off); off += (size_t)DIM * DIM * 2;
    u16* Qh  = (u16*)(ws + off); off += (size_t)ROWS * DIM * 2;
    u16* Kfr = (u16*)(ws + off); off += (size_t)ROWS * DIM * 2;
    u16* Vfr = (u16*)(ws + off); off += (size_t)ROWS * DIM * 2;
    u16* ctx = (u16*)(ws + off); off += (size_t)ROWS * DIM * 2;
    float* biasf = (float*)(ws + off); off += (size_t)BS * SEQ * 4;

    convert_all<<<5128, 256, 0, stream>>>(x, Wq, Wk, Wv, Wo, mask,
                                          xb, wqb, wkb, wvb, wob, biasf);
    gemm_qkv_fused<<<dim3(12, 64), 256, 0, stream>>>(xb, wqb, Qh, Kfr, Vfr);
    flash_attn<<<BS * HEADS * (SEQ / 64), 256, 0, stream>>>(Qh, Kfr, Vfr, biasf, ctx);
    gemm_proj<<<dim3(8, 128), 256, 0, stream>>>(ctx, wob, out);

    (void)in_sizes; (void)n_in; (void)out_size; (void)ws_size;
}